// Round 5
// baseline (755.922 us; speedup 1.0000x reference)
//
#include <hip/hip_runtime.h>
#include <hip/hip_bf16.h>

// Problem constants (fixed by the reference)
#define S     2048
#define HID   4096
#define NH    32
#define NKV   8
#define DH    128
#define KVD   1024   // NKV*DH
#define NQK   6144   // HID + 2*KVD (fused QKV output width)
#define KDIM  4096   // projection K-dim
#define SCALE_Q 0.08838834764831845f  // 1/sqrt(128), folded into Qb at GEMM epilogue

typedef unsigned short ushort_t;
typedef __attribute__((ext_vector_type(8))) __bf16 bf16x8;
typedef __attribute__((ext_vector_type(8))) unsigned short u16x8;
typedef __attribute__((ext_vector_type(4))) float f32x4;

static __device__ __forceinline__ unsigned short f2b(float f) {
    union { float f; unsigned int i; } x; x.f = f;
    unsigned int r = (x.i + 0x7fffu + ((x.i >> 16) & 1u)) >> 16;
    return (unsigned short)r;
}

// async global->LDS, 16B per lane; LDS dest = wave-uniform base + lane*16 (m97/m104).
static __device__ __forceinline__ void gload16(const void* g, void* l) {
    __builtin_amdgcn_global_load_lds(
        (const __attribute__((address_space(1))) void*)g,
        (__attribute__((address_space(3))) void*)l, 16, 0, 0);
}

// XOR chunk swizzle for the GEMM LDS tiles (2-way alias only -> free, m136).
static __device__ __forceinline__ int swz(int row, int kc) {
    return row * 4 + (kc ^ ((row >> 1) & 3));
}

// fp32 -> bf16 conversion, 4 elems/thread.
__global__ __launch_bounds__(256)
void cvt_f2b(const float* __restrict__ src, ushort_t* __restrict__ dst, int n4) {
    int i = blockIdx.x * 256 + threadIdx.x;
    if (i < n4) {
        float4 v = ((const float4*)src)[i];
        ushort4 o;
        o.x = f2b(v.x); o.y = f2b(v.y); o.z = f2b(v.z); o.w = f2b(v.w);
        ((ushort4*)dst)[i] = o;
    }
}

// m97-structure GEMM: C[M,N] = A[M,K] @ B[N,K]^T, bf16 in, fp32 accum.
// 128x128 tile, BK=32, 4 waves in 2x2; wave owns 64x64 (4x4 MFMA tiles).
// MODE 0: fp32 C. MODE 1: fused QKV epilogue (Q pre-scaled by 1/sqrt(d); V transposed).
template <int MODE>
__global__ __launch_bounds__(256)
void gemm128(const ushort_t* __restrict__ A, const ushort_t* __restrict__ B,
             float* __restrict__ Cf, ushort_t* __restrict__ Qb,
             ushort_t* __restrict__ Kb, ushort_t* __restrict__ Vt,
             int M, int N, int K) {
    __shared__ ushort_t As[128 * 32];
    __shared__ ushort_t Bs[128 * 32];

    const int tid   = threadIdx.x;
    const int w     = tid >> 6;
    const int lane  = tid & 63;
    const int mlane = lane & 15;
    const int q4    = lane >> 4;
    const int wr    = w >> 1, wc = w & 1;
    const int m0    = blockIdx.y * 128;
    const int n0    = blockIdx.x * 128;

    const int r0 = tid >> 2,        k0c = (tid & 3) ^ ((r0 >> 1) & 3);
    const int r1 = 64 + (tid >> 2), k1c = (tid & 3) ^ ((r1 >> 1) & 3);
    const ushort_t* ap0 = A + (size_t)(m0 + r0) * K + k0c * 8;
    const ushort_t* ap1 = A + (size_t)(m0 + r1) * K + k1c * 8;
    const ushort_t* bp0 = B + (size_t)(n0 + r0) * K + k0c * 8;
    const ushort_t* bp1 = B + (size_t)(n0 + r1) * K + k1c * 8;
    ushort_t* lA0 = &As[(w * 64) * 8];
    ushort_t* lA1 = &As[(256 + w * 64) * 8];
    ushort_t* lB0 = &Bs[(w * 64) * 8];
    ushort_t* lB1 = &Bs[(256 + w * 64) * 8];

    const ushort_t* afp[4];
    const ushort_t* bfp[4];
#pragma unroll
    for (int mt = 0; mt < 4; mt++) afp[mt] = &As[swz(wr * 64 + mt * 16 + mlane, q4) * 8];
#pragma unroll
    for (int nt = 0; nt < 4; nt++) bfp[nt] = &Bs[swz(wc * 64 + nt * 16 + mlane, q4) * 8];

    f32x4 acc[4][4];
#pragma unroll
    for (int i = 0; i < 4; i++)
#pragma unroll
        for (int j = 0; j < 4; j++) acc[i][j] = (f32x4)(0.0f);

    for (int k0 = 0; k0 < K; k0 += 32) {
        __syncthreads();
        gload16(ap0 + k0, lA0);
        gload16(ap1 + k0, lA1);
        gload16(bp0 + k0, lB0);
        gload16(bp1 + k0, lB1);
        __syncthreads();

        bf16x8 af[4], bf[4];
#pragma unroll
        for (int mt = 0; mt < 4; mt++) af[mt] = *(const bf16x8*)afp[mt];
#pragma unroll
        for (int nt = 0; nt < 4; nt++) bf[nt] = *(const bf16x8*)bfp[nt];
#pragma unroll
        for (int mt = 0; mt < 4; mt++)
#pragma unroll
            for (int nt = 0; nt < 4; nt++)
                acc[mt][nt] = __builtin_amdgcn_mfma_f32_16x16x32_bf16(
                    af[mt], bf[nt], acc[mt][nt], 0, 0, 0);
    }

#pragma unroll
    for (int mt = 0; mt < 4; mt++) {
#pragma unroll
        for (int nt = 0; nt < 4; nt++) {
            int row = m0 + wr * 64 + mt * 16 + q4 * 4;
            int col = n0 + wc * 64 + nt * 16 + mlane;
            if (MODE == 0) {
#pragma unroll
                for (int r = 0; r < 4; r++)
                    Cf[(size_t)(row + r) * N + col] = acc[mt][nt][r];
            } else {
                if (n0 < HID) {               // Q region: pre-scale by 1/sqrt(d)
#pragma unroll
                    for (int r = 0; r < 4; r++)
                        Qb[(size_t)(row + r) * HID + col] = f2b(acc[mt][nt][r] * SCALE_Q);
                } else if (n0 < HID + KVD) {  // K region
                    int c2 = col - HID;
#pragma unroll
                    for (int r = 0; r < 4; r++)
                        Kb[(size_t)(row + r) * KVD + c2] = f2b(acc[mt][nt][r]);
                } else {                      // V region: write transposed [KVD][S]
                    int c2 = col - (HID + KVD);
                    ushort4 o;
                    o.x = f2b(acc[mt][nt][0]); o.y = f2b(acc[mt][nt][1]);
                    o.z = f2b(acc[mt][nt][2]); o.w = f2b(acc[mt][nt][3]);
                    *(ushort4*)(Vt + (size_t)c2 * S + row) = o;
                }
            }
        }
    }
}

// Transposed-scores MFMA flash attention, StreamingLLM mask.
// Grid: (head, 64-q tile); 4 independent waves, wave w owns q-rows [qb, qb+16).
// No __syncthreads: K/V fragments load directly from global (line-coalesced, L2-hot).
// S^T = K.Q^T  (A=K-frag m=key, B=Q-frag n=q) -> C-layout col=q(lane&15),
// row=key(q4*4+r). Softmax: 15 in-lane ops + 2 shuffles per 64-key tile.
// O^T = V.P^T  (A=V-frag from Vt, B=P^T via wave-private LDS round-trip).
__global__ __launch_bounds__(256)
void attn_mfma2(const ushort_t* __restrict__ Qb, const ushort_t* __restrict__ Kb,
                const ushort_t* __restrict__ Vt, ushort_t* __restrict__ O,
                const int* __restrict__ n_init_p, const int* __restrict__ n_local_p) {
    __shared__ ushort_t Pt[4][16][72];   // [wave][q][64 keys + pad]

    const int n_init = *n_init_p, n_local = *n_local_p;
    const int tid   = threadIdx.x;
    const int w     = tid >> 6;
    const int lane  = tid & 63;
    const int mlane = lane & 15;
    const int q4    = lane >> 4;
    const int h     = blockIdx.x >> 5;
    const int qt    = blockIdx.x & 31;
    const int kh    = h >> 2;                // GQA: 4 q-heads per kv-head
    const int qb    = qt * 64 + w * 16;      // first q-row of this wave
    const int qi    = qb + mlane;            // this lane's q index

    // Q fragments (B-operand): B[n=q=mlane][k=ks*32+q4*8+j]; Qb pre-scaled.
    bf16x8 qf[4];
    {
        const ushort_t* qp = Qb + (size_t)qi * HID + h * DH + q4 * 8;
#pragma unroll
        for (int ks = 0; ks < 4; ks++) qf[ks] = *(const bf16x8*)(qp + ks * 32);
    }

    f32x4 oacc[8];                           // O^T: row d=dt*16+q4*4+r, col q=mlane
#pragma unroll
    for (int i = 0; i < 8; i++) oacc[i] = (f32x4)(0.0f);
    float mrow = -1e30f, lrow = 0.0f;        // per-q softmax state (q = mlane)

    int wstart = qb - n_local + 1; if (wstart < 0) wstart = 0;
    const int tw   = (wstart <= n_init) ? 0 : (wstart >> 6);
    const int tmax = (qb + 15) >> 6;

    const ushort_t* kbase = Kb + kh * DH + q4 * 8;
    const ushort_t* vbase = Vt + (size_t)(kh * DH + mlane) * S + q4 * 8;
    ushort_t* ptw = &Pt[w][0][0];

    for (int t = 0; t <= tmax; t++) {
        if (t > 0 && t < tw) continue;       // gap between sink tile and window
        const int j0 = t * 64;

        // QK^T: 4 key-groups x 4 k-steps. A=K-frag: A[m=key g*16+mlane][k].
        f32x4 sacc[4];
#pragma unroll
        for (int g = 0; g < 4; g++) {
            sacc[g] = (f32x4)(0.0f);
            const ushort_t* kp = kbase + (size_t)(j0 + g * 16 + mlane) * KVD;
#pragma unroll
            for (int ks = 0; ks < 4; ks++) {
                bf16x8 kf = *(const bf16x8*)(kp + ks * 32);
                sacc[g] = __builtin_amdgcn_mfma_f32_16x16x32_bf16(kf, qf[ks], sacc[g], 0, 0, 0);
            }
        }

        const bool boundary = !((j0 + 63 <= qb) && (qb + 15 - j0 < n_local));

        // Mask + tile max (in-lane over 16 regs, then 2 shuffles across q4)
        float sc[4][4];
        float tm = -1e30f;
#pragma unroll
        for (int g = 0; g < 4; g++)
#pragma unroll
            for (int r = 0; r < 4; r++) {
                float s = sacc[g][r];
                if (boundary) {
                    int j = j0 + g * 16 + q4 * 4 + r;
                    bool ok = (j <= qi) && ((j < n_init) || (qi - j < n_local));
                    s = ok ? s : -1e30f;
                }
                sc[g][r] = s;
                tm = fmaxf(tm, s);
            }
        tm = fmaxf(tm, __shfl_xor(tm, 16));
        tm = fmaxf(tm, __shfl_xor(tm, 32));

        float mnew  = fmaxf(mrow, tm);
        float alpha = __expf(mrow - mnew);
        float ls = 0.0f;
#pragma unroll
        for (int g = 0; g < 4; g++) {
            ushort4 pw;
            float p0 = __expf(sc[g][0] - mnew);
            float p1 = __expf(sc[g][1] - mnew);
            float p2 = __expf(sc[g][2] - mnew);
            float p3 = __expf(sc[g][3] - mnew);
            ls += (p0 + p1) + (p2 + p3);
            pw.x = f2b(p0); pw.y = f2b(p1); pw.z = f2b(p2); pw.w = f2b(p3);
            // P^T pack: keys g*16+q4*4+{0..3} for q=mlane
            *(ushort4*)(ptw + mlane * 72 + g * 16 + q4 * 4) = pw;
        }
        ls += __shfl_xor(ls, 16);
        ls += __shfl_xor(ls, 32);
        lrow = lrow * alpha + ls;
        mrow = mnew;
#pragma unroll
        for (int dt = 0; dt < 8; dt++) oacc[dt] *= alpha;

        // PV: A=V-frag (m=d), B=P^T-frag (n=q) read back from wave-private LDS.
#pragma unroll
        for (int s = 0; s < 2; s++) {
            bf16x8 pf = *(const bf16x8*)(ptw + mlane * 72 + s * 32 + q4 * 8);
#pragma unroll
            for (int dt = 0; dt < 8; dt++) {
                bf16x8 vf = *(const bf16x8*)(vbase + (size_t)(dt * 16) * S + j0 + s * 32);
                oacc[dt] = __builtin_amdgcn_mfma_f32_16x16x32_bf16(vf, pf, oacc[dt], 0, 0, 0);
            }
        }
    }

    // Epilogue: O[q][h*DH + d], d = dt*16 + q4*4 + r (4 consecutive dims/store)
    {
        float inv = 1.0f / lrow;
        ushort_t* op = O + (size_t)qi * HID + h * DH + q4 * 4;
#pragma unroll
        for (int dt = 0; dt < 8; dt++) {
            ushort4 o;
            o.x = f2b(oacc[dt][0] * inv);
            o.y = f2b(oacc[dt][1] * inv);
            o.z = f2b(oacc[dt][2] * inv);
            o.w = f2b(oacc[dt][3] * inv);
            *(ushort4*)(op + dt * 16) = o;
        }
    }
}

extern "C" void kernel_launch(void* const* d_in, const int* in_sizes, int n_in,
                              void* d_out, int out_size, void* d_ws, size_t ws_size,
                              hipStream_t stream) {
    const float* H  = (const float*)d_in[0];
    const float* Wq = (const float*)d_in[1];
    const float* Wk = (const float*)d_in[2];
    const float* Wv = (const float*)d_in[3];
    const float* Wo = (const float*)d_in[4];
    const int* n_init_p  = (const int*)d_in[5];
    const int* n_local_p = (const int*)d_in[6];

    // Workspace: Hb 16.8 | Wbuf 50.3 (QKV concat; reused for Wo) | Qb 16.8 |
    //            Kb 4.2 | Vt 4.2  => ~92.3 MB
    char* p = (char*)d_ws;
    ushort_t* Hb   = (ushort_t*)p;  p += (size_t)S * HID * 2;
    ushort_t* Wbuf = (ushort_t*)p;  p += (size_t)NQK * KDIM * 2;
    ushort_t* Qb   = (ushort_t*)p;  p += (size_t)S * HID * 2;
    ushort_t* Kb   = (ushort_t*)p;  p += (size_t)S * KVD * 2;
    ushort_t* Vt   = (ushort_t*)p;
    ushort_t* Ab   = Hb;  // Hb dead after QKV GEMM

    dim3 blk(256);
    const int nH = S * HID / 4, nWq = HID * KDIM / 4, nWk = KVD * KDIM / 4;

    cvt_f2b<<<dim3((nH  + 255) / 256), blk, 0, stream>>>(H,  Hb, nH);
    cvt_f2b<<<dim3((nWq + 255) / 256), blk, 0, stream>>>(Wq, Wbuf, nWq);
    cvt_f2b<<<dim3((nWk + 255) / 256), blk, 0, stream>>>(Wk, Wbuf + (size_t)HID * KDIM, nWk);
    cvt_f2b<<<dim3((nWk + 255) / 256), blk, 0, stream>>>(Wv, Wbuf + (size_t)(HID + KVD) * KDIM, nWk);
    gemm128<1><<<dim3(NQK / 128, S / 128), blk, 0, stream>>>(
        Hb, Wbuf, nullptr, Qb, Kb, Vt, S, NQK, KDIM);
    attn_mfma2<<<dim3(NH * (S / 64)), blk, 0, stream>>>(Qb, Kb, Vt, Ab, n_init_p, n_local_p);
    cvt_f2b<<<dim3((nWq + 255) / 256), blk, 0, stream>>>(Wo, Wbuf, nWq);
    gemm128<0><<<dim3(HID / 128, S / 128), blk, 0, stream>>>(
        Ab, Wbuf, (float*)d_out, nullptr, nullptr, nullptr, S, HID, KDIM);
}